// Round 2
// baseline (1183.503 us; speedup 1.0000x reference)
//
#include <hip/hip_runtime.h>
#include <math.h>

#define TB1 4
#define TB2 16

__device__ __forceinline__ float4 ldg4(const float* p) { return *(const float4*)p; }

// ---------------------------------------------------------------------------
// Kernel 1: up router + up experts + gelu  ->  h (fp32 [N][4096]) in workspace
// ---------------------------------------------------------------------------
__global__ __launch_bounds__(256, 3) void up_kernel(
    const float* __restrict__ x,        // [N][1024]
    const float* __restrict__ Wup,      // [64][1024]
    const float* __restrict__ Aup,      // [64][64][32]
    const float* __restrict__ Bup,      // [64][64][32]
    const float* __restrict__ scale_up, // [1]
    const float* __restrict__ bias_up,  // [4096]
    float* __restrict__ h)              // [N][4096]
{
    __shared__ __align__(16) float xs[TB1 * 1024];   // 16 KB
    __shared__ __align__(16) float buf[6912];        // wcs[64*68] | as[64*36]+bs[64*36]+t1[64*36] | yl[64*68]
    __shared__ __align__(16) float lp[4 * TB1 * 64];
    __shared__ __align__(16) float logits[TB1 * 64];
    __shared__ int   seli[TB1 * 2];
    __shared__ float selp[TB1 * 2];

    const int tid = threadIdx.x;
    const long long blockTok = (long long)blockIdx.x * TB1;

    // ---- stage x tile (coalesced) ----
    {
        const float* src = x + blockTok * 1024;
#pragma unroll
        for (int q = 0; q < TB1; ++q) {
            int flat = tid * 4 + q * 1024;
            *(float4*)&xs[flat] = ldg4(src + flat);
        }
    }

    // ---- up router ----
    float racc[TB1] = {0.f, 0.f, 0.f, 0.f};
    float* wcs = buf; // [64][68]
    const int e = tid & 63, jsl = tid >> 6;
    for (int kc = 0; kc < 1024; kc += 64) {
        __syncthreads();
#pragma unroll
        for (int r = 0; r < 4; ++r) {
            int row = (tid >> 4) + r * 16;
            int col = (tid & 15) * 4;
            *(float4*)&wcs[row * 68 + col] = ldg4(&Wup[row * 1024 + kc + col]);
        }
        __syncthreads();
#pragma unroll
        for (int ks = 0; ks < 4; ++ks) {
            int kk = jsl * 16 + ks * 4;
            float4 w = *(float4*)&wcs[e * 68 + kk];
#pragma unroll
            for (int t = 0; t < TB1; ++t) {
                float4 xv = *(float4*)&xs[t * 1024 + kc + kk];
                racc[t] += w.x * xv.x + w.y * xv.y + w.z * xv.z + w.w * xv.w;
            }
        }
    }
#pragma unroll
    for (int t = 0; t < TB1; ++t) lp[(jsl * TB1 + t) * 64 + e] = racc[t];
    __syncthreads();
    logits[tid] = lp[0 * 256 + tid] + lp[1 * 256 + tid] + lp[2 * 256 + tid] + lp[3 * 256 + tid];
    __syncthreads();
    if (tid < TB1) {
        const float* lg = &logits[tid * 64];
        float v0 = -1e30f; int i0 = 0;
        for (int q = 0; q < 64; ++q) { float v = lg[q]; if (v > v0) { v0 = v; i0 = q; } }
        float v1 = -1e30f; int i1 = 0;
        for (int q = 0; q < 64; ++q) { if (q == i0) continue; float v = lg[q]; if (v > v1) { v1 = v; i1 = q; } }
        float r = expf(v1 - v0);
        float inv = 1.f / (1.f + r);
        seli[tid * 2] = i0; seli[tid * 2 + 1] = i1;
        selp[tid * 2] = inv; selp[tid * 2 + 1] = r * inv;
    }
    __syncthreads();

    // ---- up experts ----
    float* as_ = buf;          // [64][36]
    float* bs_ = buf + 2304;   // [64][36]  (pre-scaled by pw)
    float* t1_ = buf + 4608;   // [64][36]
    const float sc_up = scale_up[0];

    for (int t = 0; t < TB1; ++t) {
        float acc[16];
#pragma unroll
        for (int q = 0; q < 16; ++q) acc[q] = 0.f;

        for (int ke = 0; ke < 2; ++ke) {
            __syncthreads();
            int ex = seli[t * 2 + ke];
            float pw = selp[t * 2 + ke];
            {
                const float* A = Aup + ex * 2048;
                const float* B = Bup + ex * 2048;
#pragma unroll
                for (int q = 0; q < 2; ++q) {
                    int flat = tid * 4 + q * 1024;
                    int r = flat >> 5, c = flat & 31;
                    *(float4*)&as_[r * 36 + c] = ldg4(A + flat);
                    float4 bv = ldg4(B + flat);
                    bv.x *= pw; bv.y *= pw; bv.z *= pw; bv.w *= pw;
                    *(float4*)&bs_[r * 36 + c] = bv;
                }
            }
            __syncthreads();
            // T1[o][j] = sum_i A[o][i]*X[i][j];  o in {og, og+32}, j0..j0+3
            {
                int og = tid >> 3, j0 = (tid & 7) * 4;
                float4 s0 = make_float4(0.f, 0.f, 0.f, 0.f);
                float4 s1 = make_float4(0.f, 0.f, 0.f, 0.f);
#pragma unroll 8
                for (int i = 0; i < 32; ++i) {
                    float a0 = as_[og * 36 + i];
                    float a1 = as_[(og + 32) * 36 + i];
                    float4 xv = *(float4*)&xs[t * 1024 + i * 32 + j0];
                    s0.x += a0 * xv.x; s0.y += a0 * xv.y; s0.z += a0 * xv.z; s0.w += a0 * xv.w;
                    s1.x += a1 * xv.x; s1.y += a1 * xv.y; s1.z += a1 * xv.z; s1.w += a1 * xv.w;
                }
                *(float4*)&t1_[og * 36 + j0] = s0;
                *(float4*)&t1_[(og + 32) * 36 + j0] = s1;
            }
            __syncthreads();
            // Y[o][p] += sum_j T1[o][j]*Bs[p][j];  4x4 tile o=o0+16a, p=p0+16b
            {
                int o0 = tid >> 4, p0 = tid & 15;
#pragma unroll
                for (int jq = 0; jq < 8; ++jq) {
                    int j = jq * 4;
                    float4 tv[4], bv[4];
#pragma unroll
                    for (int a = 0; a < 4; ++a) tv[a] = *(float4*)&t1_[(o0 + 16 * a) * 36 + j];
#pragma unroll
                    for (int b = 0; b < 4; ++b) bv[b] = *(float4*)&bs_[(p0 + 16 * b) * 36 + j];
#pragma unroll
                    for (int a = 0; a < 4; ++a)
#pragma unroll
                        for (int b = 0; b < 4; ++b)
                            acc[a * 4 + b] += tv[a].x * bv[b].x + tv[a].y * bv[b].y +
                                              tv[a].z * bv[b].z + tv[a].w * bv[b].w;
                }
            }
        }
        // epilogue: transpose via LDS, then bias+gelu, coalesced write
        __syncthreads();
        {
            float* yl = buf; // [64][68]
            int o0 = tid >> 4, p0 = tid & 15;
#pragma unroll
            for (int a = 0; a < 4; ++a)
#pragma unroll
                for (int b = 0; b < 4; ++b)
                    yl[(o0 + 16 * a) * 68 + (p0 + 16 * b)] = acc[a * 4 + b] * sc_up;
        }
        __syncthreads();
        {
            long long tok = blockTok + t;
            float* hrow = h + tok * 4096;
            float* yl = buf;
#pragma unroll
            for (int q = 0; q < 4; ++q) {
                int f = tid * 16 + q * 4;
                int o = f >> 6, p = f & 63;
                float4 v = *(float4*)&yl[o * 68 + p];
                float4 bb = ldg4(&bias_up[f]);
                float4 g;
                float z;
                z = v.x + bb.x; g.x = 0.5f * z * (1.0f + erff(z * 0.70710678118654752f));
                z = v.y + bb.y; g.y = 0.5f * z * (1.0f + erff(z * 0.70710678118654752f));
                z = v.z + bb.z; g.z = 0.5f * z * (1.0f + erff(z * 0.70710678118654752f));
                z = v.w + bb.w; g.w = 0.5f * z * (1.0f + erff(z * 0.70710678118654752f));
                *(float4*)&hrow[f] = g;
            }
        }
    }
}

// ---------------------------------------------------------------------------
// Kernel 2: down router + down experts  ->  out (fp32 [N][1024])
// ---------------------------------------------------------------------------
__global__ __launch_bounds__(256, 3) void down_kernel(
    const float* __restrict__ h,        // [N][4096]
    const float* __restrict__ Wdn,      // [64][4096]
    const float* __restrict__ Adn,      // [64][32][64]
    const float* __restrict__ Bdn,      // [64][32][64]
    const float* __restrict__ scale_dn, // [1]
    const float* __restrict__ bias_dn,  // [1024]
    float* __restrict__ out)            // [N][1024]
{
    __shared__ __align__(16) float wcs[64 * 68];   // router W chunk | later xls[64][68]
    __shared__ __align__(16) float rbuf[6528];     // hcs[16*68]+lp[4096] | adl+bdl+t1l (each 32*68)
    __shared__ __align__(16) float logits[TB2 * 64];
    __shared__ int   seli[TB2 * 2];
    __shared__ float selp[TB2 * 2];

    const int tid = threadIdx.x;
    const long long tokbase = (long long)blockIdx.x * TB2;
    float* hcs = rbuf;          // [16][68]
    float* lp  = rbuf + 1088;   // [4][16][64]

    // ---- down router ----
    float racc[TB2];
#pragma unroll
    for (int t = 0; t < TB2; ++t) racc[t] = 0.f;
    const int e = tid & 63, jsl = tid >> 6;

    for (int kc = 0; kc < 4096; kc += 64) {
        __syncthreads();
#pragma unroll
        for (int r = 0; r < 4; ++r) {
            int row = (tid >> 4) + r * 16;
            int col = (tid & 15) * 4;
            *(float4*)&wcs[row * 68 + col] = ldg4(&Wdn[row * 4096 + kc + col]);
        }
        {
            int t = tid >> 4, c = (tid & 15) * 4;
            *(float4*)&hcs[t * 68 + c] = ldg4(&h[(tokbase + t) * 4096 + kc + c]);
        }
        __syncthreads();
#pragma unroll
        for (int ks = 0; ks < 4; ++ks) {
            int kk = jsl * 16 + ks * 4;
            float4 w = *(float4*)&wcs[e * 68 + kk];
#pragma unroll
            for (int t = 0; t < TB2; ++t) {
                float4 hv = *(float4*)&hcs[t * 68 + kk];
                racc[t] += w.x * hv.x + w.y * hv.y + w.z * hv.z + w.w * hv.w;
            }
        }
    }
#pragma unroll
    for (int t = 0; t < TB2; ++t) lp[(jsl * TB2 + t) * 64 + e] = racc[t];
    __syncthreads();
#pragma unroll
    for (int q = 0; q < 4; ++q) {
        int pair = tid + q * 256;
        logits[pair] = lp[0 * 1024 + pair] + lp[1 * 1024 + pair] +
                       lp[2 * 1024 + pair] + lp[3 * 1024 + pair];
    }
    __syncthreads();
    if (tid < TB2) {
        const float* lg = &logits[tid * 64];
        float v0 = -1e30f; int i0 = 0;
        for (int q = 0; q < 64; ++q) { float v = lg[q]; if (v > v0) { v0 = v; i0 = q; } }
        float v1 = -1e30f; int i1 = 0;
        for (int q = 0; q < 64; ++q) { if (q == i0) continue; float v = lg[q]; if (v > v1) { v1 = v; i1 = q; } }
        float r = expf(v1 - v0);
        float inv = 1.f / (1.f + r);
        seli[tid * 2] = i0; seli[tid * 2 + 1] = i1;
        selp[tid * 2] = inv; selp[tid * 2 + 1] = r * inv;
    }
    __syncthreads();

    // ---- down experts ----
    float* xls = wcs;              // [64][68]
    float* adl = rbuf;             // [32][68]
    float* bdl = rbuf + 2176;      // [32][68]  (pre-scaled by pw)
    float* t1l = rbuf + 4352;      // [32][68]  (also yl[32][32] in epilogue)
    const float sc_dn = scale_dn[0];

    for (int t = 0; t < TB2; ++t) {
        long long tok = tokbase + t;
        __syncthreads();
#pragma unroll
        for (int q = 0; q < 4; ++q) {
            int flat = tid * 4 + q * 1024;
            int i = flat >> 6, c = flat & 63;
            *(float4*)&xls[i * 68 + c] = ldg4(&h[tok * 4096 + flat]);
        }
        float acc4[4] = {0.f, 0.f, 0.f, 0.f};
        for (int ke = 0; ke < 2; ++ke) {
            __syncthreads();
            int ex = seli[t * 2 + ke];
            float pw = selp[t * 2 + ke];
            {
                const float* A = Adn + ex * 2048;
                const float* B = Bdn + ex * 2048;
#pragma unroll
                for (int q = 0; q < 2; ++q) {
                    int flat = tid * 4 + q * 1024;
                    int r = flat >> 6, c = flat & 63;
                    *(float4*)&adl[r * 68 + c] = ldg4(A + flat);
                    float4 bv = ldg4(B + flat);
                    bv.x *= pw; bv.y *= pw; bv.z *= pw; bv.w *= pw;
                    *(float4*)&bdl[r * 68 + c] = bv;
                }
            }
            __syncthreads();
            // T1[o][j]: o in {og, og+16}, j0..j0+3
            {
                int og = tid >> 4, j0 = (tid & 15) * 4;
                float4 s0 = make_float4(0.f, 0.f, 0.f, 0.f);
                float4 s1 = make_float4(0.f, 0.f, 0.f, 0.f);
#pragma unroll 8
                for (int i = 0; i < 64; ++i) {
                    float a0 = adl[og * 68 + i];
                    float a1 = adl[(og + 16) * 68 + i];
                    float4 xv = *(float4*)&xls[i * 68 + j0];
                    s0.x += a0 * xv.x; s0.y += a0 * xv.y; s0.z += a0 * xv.z; s0.w += a0 * xv.w;
                    s1.x += a1 * xv.x; s1.y += a1 * xv.y; s1.z += a1 * xv.z; s1.w += a1 * xv.w;
                }
                *(float4*)&t1l[og * 68 + j0] = s0;
                *(float4*)&t1l[(og + 16) * 68 + j0] = s1;
            }
            __syncthreads();
            // Y 2x2 tile: o in {o0,o0+16}, p in {p0,p0+16}
            {
                int o0 = tid >> 4, p0 = tid & 15;
#pragma unroll
                for (int jq = 0; jq < 16; ++jq) {
                    int j = jq * 4;
                    float4 t0 = *(float4*)&t1l[o0 * 68 + j];
                    float4 t1 = *(float4*)&t1l[(o0 + 16) * 68 + j];
                    float4 b0 = *(float4*)&bdl[p0 * 68 + j];
                    float4 b1 = *(float4*)&bdl[(p0 + 16) * 68 + j];
                    acc4[0] += t0.x * b0.x + t0.y * b0.y + t0.z * b0.z + t0.w * b0.w;
                    acc4[1] += t0.x * b1.x + t0.y * b1.y + t0.z * b1.z + t0.w * b1.w;
                    acc4[2] += t1.x * b0.x + t1.y * b0.y + t1.z * b0.z + t1.w * b0.w;
                    acc4[3] += t1.x * b1.x + t1.y * b1.y + t1.z * b1.z + t1.w * b1.w;
                }
            }
        }
        // epilogue: transpose via LDS then bias + coalesced float4 write
        __syncthreads();
        {
            float* yl = t1l; // [32][32], stride 32
            int o0 = tid >> 4, p0 = tid & 15;
            yl[o0 * 32 + p0]             = acc4[0] * sc_dn;
            yl[o0 * 32 + p0 + 16]        = acc4[1] * sc_dn;
            yl[(o0 + 16) * 32 + p0]      = acc4[2] * sc_dn;
            yl[(o0 + 16) * 32 + p0 + 16] = acc4[3] * sc_dn;
        }
        __syncthreads();
        {
            float* yl = t1l;
            float4 v = *(float4*)&yl[tid * 4];
            float4 bb = ldg4(&bias_dn[tid * 4]);
            v.x += bb.x; v.y += bb.y; v.z += bb.z; v.w += bb.w;
            *(float4*)&out[tok * 1024 + tid * 4] = v;
        }
    }
}

extern "C" void kernel_launch(void* const* d_in, const int* in_sizes, int n_in,
                              void* d_out, int out_size, void* d_ws, size_t ws_size,
                              hipStream_t stream) {
    const float* x   = (const float*)d_in[0];
    const float* Wup = (const float*)d_in[1];
    const float* Aup = (const float*)d_in[2];
    const float* Bup = (const float*)d_in[3];
    const float* scu = (const float*)d_in[4];
    const float* biu = (const float*)d_in[5];
    const float* Wdn = (const float*)d_in[6];
    const float* Adn = (const float*)d_in[7];
    const float* Bdn = (const float*)d_in[8];
    const float* scd = (const float*)d_in[9];
    const float* bid = (const float*)d_in[10];
    float* out = (float*)d_out;
    float* h   = (float*)d_ws;   // [N][4096] fp32 = 128 MB for N=8192

    const int N = in_sizes[0] / 1024;

    hipLaunchKernelGGL(up_kernel, dim3(N / TB1), dim3(256), 0, stream,
                       x, Wup, Aup, Bup, scu, biu, h);
    hipLaunchKernelGGL(down_kernel, dim3(N / TB2), dim3(256), 0, stream,
                       h, Wdn, Adn, Bdn, scd, bid, out);
}

// Round 3
// 590.245 us; speedup vs baseline: 2.0051x; 2.0051x over previous
//
#include <hip/hip_runtime.h>
#include <math.h>

#define TB1 4
#define TB2 16

__device__ __forceinline__ float4 ldg4(const float* p) { return *(const float4*)p; }

// ---------------------------------------------------------------------------
// Kernel 1: up router + up experts + gelu  ->  h (fp32 [N][4096]) in workspace
// ---------------------------------------------------------------------------
__global__ __launch_bounds__(256, 3) void up_kernel(
    const float* __restrict__ x,        // [N][1024]
    const float* __restrict__ Wup,      // [64][1024]
    const float* __restrict__ Aup,      // [64][64][32]
    const float* __restrict__ Bup,      // [64][64][32]
    const float* __restrict__ scale_up, // [1]
    const float* __restrict__ bias_up,  // [4096]
    float* __restrict__ h)              // [N][4096]
{
    __shared__ __align__(16) float xs[TB1 * 1024];   // 16 KB
    __shared__ __align__(16) float buf[6912];        // wcs[64*68] | as/bs/t1 [64*36] | yl[64*68]
    __shared__ __align__(16) float lp[4 * TB1 * 64];
    __shared__ __align__(16) float logits[TB1 * 64];
    __shared__ int   seli[TB1 * 2];
    __shared__ float selp[TB1 * 2];

    const int tid = threadIdx.x;
    const long long blockTok = (long long)blockIdx.x * TB1;

    // ---- stage x tile (coalesced) ----
    {
        const float* src = x + blockTok * 1024;
#pragma unroll
        for (int q = 0; q < TB1; ++q) {
            int flat = tid * 4 + q * 1024;
            *(float4*)&xs[flat] = ldg4(src + flat);
        }
    }

    // ---- up router: 2 experts per thread ----
    float racc0[TB1] = {0.f, 0.f, 0.f, 0.f};
    float racc1[TB1] = {0.f, 0.f, 0.f, 0.f};
    float* wcs = buf; // [64][68]
    const int e2 = tid & 31, jsl = tid >> 5; // jsl 0..7, slice of 8 floats
    for (int kc = 0; kc < 1024; kc += 64) {
        __syncthreads();
#pragma unroll
        for (int r = 0; r < 4; ++r) {
            int row = (tid >> 4) + r * 16;
            int col = (tid & 15) * 4;
            *(float4*)&wcs[row * 68 + col] = ldg4(&Wup[row * 1024 + kc + col]);
        }
        __syncthreads();
#pragma unroll
        for (int ks = 0; ks < 2; ++ks) {
            int kk = jsl * 8 + ks * 4;
            float4 w0 = *(float4*)&wcs[e2 * 68 + kk];
            float4 w1 = *(float4*)&wcs[(e2 + 32) * 68 + kk];
#pragma unroll
            for (int t = 0; t < TB1; ++t) {
                float4 xv = *(float4*)&xs[t * 1024 + kc + kk];
                racc0[t] += w0.x * xv.x + w0.y * xv.y + w0.z * xv.z + w0.w * xv.w;
                racc1[t] += w1.x * xv.x + w1.y * xv.y + w1.z * xv.z + w1.w * xv.w;
            }
        }
    }
#pragma unroll
    for (int t = 0; t < TB1; ++t) {
        racc0[t] += __shfl_xor(racc0[t], 32);
        racc1[t] += __shfl_xor(racc1[t], 32);
    }
    {
        const int wv = tid >> 6;
        if ((tid & 32) == 0) {
#pragma unroll
            for (int t = 0; t < TB1; ++t) {
                lp[(wv * TB1 + t) * 64 + e2]      = racc0[t];
                lp[(wv * TB1 + t) * 64 + e2 + 32] = racc1[t];
            }
        }
    }
    __syncthreads();
    logits[tid] = lp[0 * 256 + tid] + lp[1 * 256 + tid] + lp[2 * 256 + tid] + lp[3 * 256 + tid];
    __syncthreads();
    if (tid < TB1) {
        const float* lg = &logits[tid * 64];
        float v0 = -1e30f; int i0 = 0;
        for (int q = 0; q < 64; ++q) { float v = lg[q]; if (v > v0) { v0 = v; i0 = q; } }
        float v1 = -1e30f; int i1 = 0;
        for (int q = 0; q < 64; ++q) { if (q == i0) continue; float v = lg[q]; if (v > v1) { v1 = v; i1 = q; } }
        float r = expf(v1 - v0);
        float inv = 1.f / (1.f + r);
        seli[tid * 2] = i0; seli[tid * 2 + 1] = i1;
        selp[tid * 2] = inv; selp[tid * 2 + 1] = r * inv;
    }
    __syncthreads();

    // ---- up experts ----
    float* as_ = buf;          // [64][36]
    float* bs_ = buf + 2304;   // [64][36]  (pre-scaled by pw)
    float* t1_ = buf + 4608;   // [64][36]
    const float sc_up = scale_up[0];

    for (int t = 0; t < TB1; ++t) {
        float acc[16];
#pragma unroll
        for (int q = 0; q < 16; ++q) acc[q] = 0.f;

        for (int ke = 0; ke < 2; ++ke) {
            __syncthreads();
            int ex = seli[t * 2 + ke];
            float pw = selp[t * 2 + ke];
            {
                const float* A = Aup + ex * 2048;
                const float* B = Bup + ex * 2048;
#pragma unroll
                for (int q = 0; q < 2; ++q) {
                    int flat = tid * 4 + q * 1024;
                    int r = flat >> 5, c = flat & 31;
                    *(float4*)&as_[r * 36 + c] = ldg4(A + flat);
                    float4 bv = ldg4(B + flat);
                    bv.x *= pw; bv.y *= pw; bv.z *= pw; bv.w *= pw;
                    *(float4*)&bs_[r * 36 + c] = bv;
                }
            }
            __syncthreads();
            // T1[o][j] = sum_i A[o][i]*X[i][j];  o in {og, og+32}, j0..j0+3
            {
                int og = tid >> 3, j0 = (tid & 7) * 4;
                float4 s0 = make_float4(0.f, 0.f, 0.f, 0.f);
                float4 s1 = make_float4(0.f, 0.f, 0.f, 0.f);
#pragma unroll 8
                for (int i = 0; i < 32; ++i) {
                    float a0 = as_[og * 36 + i];
                    float a1 = as_[(og + 32) * 36 + i];
                    float4 xv = *(float4*)&xs[t * 1024 + i * 32 + j0];
                    s0.x += a0 * xv.x; s0.y += a0 * xv.y; s0.z += a0 * xv.z; s0.w += a0 * xv.w;
                    s1.x += a1 * xv.x; s1.y += a1 * xv.y; s1.z += a1 * xv.z; s1.w += a1 * xv.w;
                }
                *(float4*)&t1_[og * 36 + j0] = s0;
                *(float4*)&t1_[(og + 32) * 36 + j0] = s1;
            }
            __syncthreads();
            // Y[o][p] += sum_j T1[o][j]*Bs[p][j]; 4x4 tile, minimal live set,
            // unroll 1 to stop cross-iteration load hoisting (R2 spill fix)
            {
                int o0 = tid >> 4, p0 = tid & 15;
#pragma unroll 1
                for (int jq = 0; jq < 8; ++jq) {
                    int j = jq * 4;
                    float4 t0 = *(float4*)&t1_[o0 * 36 + j];
                    float4 t1v = *(float4*)&t1_[(o0 + 16) * 36 + j];
                    float4 t2 = *(float4*)&t1_[(o0 + 32) * 36 + j];
                    float4 t3 = *(float4*)&t1_[(o0 + 48) * 36 + j];
#pragma unroll
                    for (int b = 0; b < 4; ++b) {
                        float4 bv = *(float4*)&bs_[(p0 + 16 * b) * 36 + j];
                        acc[0 * 4 + b] += t0.x * bv.x + t0.y * bv.y + t0.z * bv.z + t0.w * bv.w;
                        acc[1 * 4 + b] += t1v.x * bv.x + t1v.y * bv.y + t1v.z * bv.z + t1v.w * bv.w;
                        acc[2 * 4 + b] += t2.x * bv.x + t2.y * bv.y + t2.z * bv.z + t2.w * bv.w;
                        acc[3 * 4 + b] += t3.x * bv.x + t3.y * bv.y + t3.z * bv.z + t3.w * bv.w;
                    }
                }
            }
        }
        // epilogue: transpose via LDS, then bias+gelu, wave-contiguous 1KB stores
        __syncthreads();
        {
            float* yl = buf; // [64][68]
            int o0 = tid >> 4, p0 = tid & 15;
#pragma unroll
            for (int a = 0; a < 4; ++a)
#pragma unroll
                for (int b = 0; b < 4; ++b)
                    yl[(o0 + 16 * a) * 68 + (p0 + 16 * b)] = acc[a * 4 + b] * sc_up;
        }
        __syncthreads();
        {
            long long tok = blockTok + t;
            float* hrow = h + tok * 4096;
            float* yl = buf;
#pragma unroll
            for (int q = 0; q < 4; ++q) {
                int f = q * 1024 + tid * 4;
                int o = f >> 6, p = f & 63;
                float4 v = *(float4*)&yl[o * 68 + p];
                float4 bb = ldg4(&bias_up[f]);
                float4 g;
                float z;
                z = v.x + bb.x; g.x = 0.5f * z * (1.0f + erff(z * 0.70710678118654752f));
                z = v.y + bb.y; g.y = 0.5f * z * (1.0f + erff(z * 0.70710678118654752f));
                z = v.z + bb.z; g.z = 0.5f * z * (1.0f + erff(z * 0.70710678118654752f));
                z = v.w + bb.w; g.w = 0.5f * z * (1.0f + erff(z * 0.70710678118654752f));
                *(float4*)&hrow[f] = g;
            }
        }
    }
}

// ---------------------------------------------------------------------------
// Kernel 2: down router + down experts  ->  out (fp32 [N][1024])
// ---------------------------------------------------------------------------
__global__ __launch_bounds__(256, 3) void down_kernel(
    const float* __restrict__ h,        // [N][4096]
    const float* __restrict__ Wdn,      // [64][4096]
    const float* __restrict__ Adn,      // [64][32][64]
    const float* __restrict__ Bdn,      // [64][32][64]
    const float* __restrict__ scale_dn, // [1]
    const float* __restrict__ bias_dn,  // [1024]
    float* __restrict__ out)            // [N][1024]
{
    __shared__ __align__(16) float wcs[64 * 68];   // router W chunk | later xls[64][68]
    __shared__ __align__(16) float rbuf[6528];     // hcs[16*68]+lp[4096] | adl+bdl+t1l (each 32*68)
    __shared__ __align__(16) float logits[TB2 * 64];
    __shared__ int   seli[TB2 * 2];
    __shared__ float selp[TB2 * 2];

    const int tid = threadIdx.x;
    const long long tokbase = (long long)blockIdx.x * TB2;
    float* hcs = rbuf;          // [16][68]
    float* lp  = rbuf + 1088;   // [4][16][64]

    // ---- down router: 2 experts per thread ----
    float racc0[TB2], racc1[TB2];
#pragma unroll
    for (int t = 0; t < TB2; ++t) { racc0[t] = 0.f; racc1[t] = 0.f; }
    const int e2 = tid & 31, jsl = tid >> 5; // jsl 0..7, slice of 8 floats

    for (int kc = 0; kc < 4096; kc += 64) {
        __syncthreads();
#pragma unroll
        for (int r = 0; r < 4; ++r) {
            int row = (tid >> 4) + r * 16;
            int col = (tid & 15) * 4;
            *(float4*)&wcs[row * 68 + col] = ldg4(&Wdn[row * 4096 + kc + col]);
        }
        {
            int t = tid >> 4, c = (tid & 15) * 4;
            *(float4*)&hcs[t * 68 + c] = ldg4(&h[(tokbase + t) * 4096 + kc + c]);
        }
        __syncthreads();
#pragma unroll
        for (int ks = 0; ks < 2; ++ks) {
            int kk = jsl * 8 + ks * 4;
            float4 w0 = *(float4*)&wcs[e2 * 68 + kk];
            float4 w1 = *(float4*)&wcs[(e2 + 32) * 68 + kk];
#pragma unroll 8
            for (int t = 0; t < TB2; ++t) {
                float4 hv = *(float4*)&hcs[t * 68 + kk];
                racc0[t] += w0.x * hv.x + w0.y * hv.y + w0.z * hv.z + w0.w * hv.w;
                racc1[t] += w1.x * hv.x + w1.y * hv.y + w1.z * hv.z + w1.w * hv.w;
            }
        }
    }
#pragma unroll
    for (int t = 0; t < TB2; ++t) {
        racc0[t] += __shfl_xor(racc0[t], 32);
        racc1[t] += __shfl_xor(racc1[t], 32);
    }
    {
        const int wv = tid >> 6;
        if ((tid & 32) == 0) {
#pragma unroll
            for (int t = 0; t < TB2; ++t) {
                lp[(wv * TB2 + t) * 64 + e2]      = racc0[t];
                lp[(wv * TB2 + t) * 64 + e2 + 32] = racc1[t];
            }
        }
    }
    __syncthreads();
#pragma unroll
    for (int q = 0; q < 4; ++q) {
        int pair = tid + q * 256;
        logits[pair] = lp[0 * 1024 + pair] + lp[1 * 1024 + pair] +
                       lp[2 * 1024 + pair] + lp[3 * 1024 + pair];
    }
    __syncthreads();
    if (tid < TB2) {
        const float* lg = &logits[tid * 64];
        float v0 = -1e30f; int i0 = 0;
        for (int q = 0; q < 64; ++q) { float v = lg[q]; if (v > v0) { v0 = v; i0 = q; } }
        float v1 = -1e30f; int i1 = 0;
        for (int q = 0; q < 64; ++q) { if (q == i0) continue; float v = lg[q]; if (v > v1) { v1 = v; i1 = q; } }
        float r = expf(v1 - v0);
        float inv = 1.f / (1.f + r);
        seli[tid * 2] = i0; seli[tid * 2 + 1] = i1;
        selp[tid * 2] = inv; selp[tid * 2 + 1] = r * inv;
    }
    __syncthreads();

    // ---- down experts ----
    float* xls = wcs;              // [64][68]
    float* adl = rbuf;             // [32][68]
    float* bdl = rbuf + 2176;      // [32][68]  (pre-scaled by pw)
    float* t1l = rbuf + 4352;      // [32][68]  (also yl[32][32] in epilogue)
    const float sc_dn = scale_dn[0];

    for (int t = 0; t < TB2; ++t) {
        long long tok = tokbase + t;
        __syncthreads();
#pragma unroll
        for (int q = 0; q < 4; ++q) {
            int flat = tid * 4 + q * 1024;
            int i = flat >> 6, c = flat & 63;
            *(float4*)&xls[i * 68 + c] = ldg4(&h[tok * 4096 + flat]);
        }
        float acc4[4] = {0.f, 0.f, 0.f, 0.f};
        for (int ke = 0; ke < 2; ++ke) {
            __syncthreads();
            int ex = seli[t * 2 + ke];
            float pw = selp[t * 2 + ke];
            {
                const float* A = Adn + ex * 2048;
                const float* B = Bdn + ex * 2048;
#pragma unroll
                for (int q = 0; q < 2; ++q) {
                    int flat = tid * 4 + q * 1024;
                    int r = flat >> 6, c = flat & 63;
                    *(float4*)&adl[r * 68 + c] = ldg4(A + flat);
                    float4 bv = ldg4(B + flat);
                    bv.x *= pw; bv.y *= pw; bv.z *= pw; bv.w *= pw;
                    *(float4*)&bdl[r * 68 + c] = bv;
                }
            }
            __syncthreads();
            // T1[o][j]: o in {og, og+16}, j0..j0+3
            {
                int og = tid >> 4, j0 = (tid & 15) * 4;
                float4 s0 = make_float4(0.f, 0.f, 0.f, 0.f);
                float4 s1 = make_float4(0.f, 0.f, 0.f, 0.f);
#pragma unroll 8
                for (int i = 0; i < 64; ++i) {
                    float a0 = adl[og * 68 + i];
                    float a1 = adl[(og + 16) * 68 + i];
                    float4 xv = *(float4*)&xls[i * 68 + j0];
                    s0.x += a0 * xv.x; s0.y += a0 * xv.y; s0.z += a0 * xv.z; s0.w += a0 * xv.w;
                    s1.x += a1 * xv.x; s1.y += a1 * xv.y; s1.z += a1 * xv.z; s1.w += a1 * xv.w;
                }
                *(float4*)&t1l[og * 68 + j0] = s0;
                *(float4*)&t1l[(og + 16) * 68 + j0] = s1;
            }
            __syncthreads();
            // Y 2x2 tile: o in {o0,o0+16}, p in {p0,p0+16}
            {
                int o0 = tid >> 4, p0 = tid & 15;
#pragma unroll 1
                for (int jq = 0; jq < 16; ++jq) {
                    int j = jq * 4;
                    float4 t0 = *(float4*)&t1l[o0 * 68 + j];
                    float4 t1 = *(float4*)&t1l[(o0 + 16) * 68 + j];
                    float4 b0 = *(float4*)&bdl[p0 * 68 + j];
                    float4 b1 = *(float4*)&bdl[(p0 + 16) * 68 + j];
                    acc4[0] += t0.x * b0.x + t0.y * b0.y + t0.z * b0.z + t0.w * b0.w;
                    acc4[1] += t0.x * b1.x + t0.y * b1.y + t0.z * b1.z + t0.w * b1.w;
                    acc4[2] += t1.x * b0.x + t1.y * b0.y + t1.z * b0.z + t1.w * b0.w;
                    acc4[3] += t1.x * b1.x + t1.y * b1.y + t1.z * b1.z + t1.w * b1.w;
                }
            }
        }
        // epilogue: transpose via LDS then bias + coalesced float4 write
        __syncthreads();
        {
            float* yl = t1l; // [32][32], stride 32
            int o0 = tid >> 4, p0 = tid & 15;
            yl[o0 * 32 + p0]             = acc4[0] * sc_dn;
            yl[o0 * 32 + p0 + 16]        = acc4[1] * sc_dn;
            yl[(o0 + 16) * 32 + p0]      = acc4[2] * sc_dn;
            yl[(o0 + 16) * 32 + p0 + 16] = acc4[3] * sc_dn;
        }
        __syncthreads();
        {
            float* yl = t1l;
            float4 v = *(float4*)&yl[tid * 4];
            float4 bb = ldg4(&bias_dn[tid * 4]);
            v.x += bb.x; v.y += bb.y; v.z += bb.z; v.w += bb.w;
            *(float4*)&out[tok * 1024 + tid * 4] = v;
        }
    }
}

extern "C" void kernel_launch(void* const* d_in, const int* in_sizes, int n_in,
                              void* d_out, int out_size, void* d_ws, size_t ws_size,
                              hipStream_t stream) {
    const float* x   = (const float*)d_in[0];
    const float* Wup = (const float*)d_in[1];
    const float* Aup = (const float*)d_in[2];
    const float* Bup = (const float*)d_in[3];
    const float* scu = (const float*)d_in[4];
    const float* biu = (const float*)d_in[5];
    const float* Wdn = (const float*)d_in[6];
    const float* Adn = (const float*)d_in[7];
    const float* Bdn = (const float*)d_in[8];
    const float* scd = (const float*)d_in[9];
    const float* bid = (const float*)d_in[10];
    float* out = (float*)d_out;
    float* h   = (float*)d_ws;   // [N][4096] fp32 = 128 MB for N=8192

    const int N = in_sizes[0] / 1024;

    hipLaunchKernelGGL(up_kernel, dim3(N / TB1), dim3(256), 0, stream,
                       x, Wup, Aup, Bup, scu, biu, h);
    hipLaunchKernelGGL(down_kernel, dim3(N / TB2), dim3(256), 0, stream,
                       h, Wdn, Adn, Bdn, scd, bid, out);
}

// Round 4
// 387.257 us; speedup vs baseline: 3.0561x; 1.5242x over previous
//
#include <hip/hip_runtime.h>
#include <math.h>

#define TB1 4
#define TB2 16

typedef __attribute__((ext_vector_type(8))) short s8v;
typedef __attribute__((ext_vector_type(4))) short s4v;
typedef __attribute__((ext_vector_type(4))) float f4v;

__device__ __forceinline__ float4 ldg4(const float* p) { return *(const float4*)p; }

// fp32 -> bf16 round-to-nearest-even
__device__ __forceinline__ short f2b(float f) {
    union { float f; unsigned u; } v; v.f = f;
    unsigned r = v.u + 0x7fffu + ((v.u >> 16) & 1u);
    return (short)(r >> 16);
}
__device__ __forceinline__ s8v pack8(float4 a, float4 b) {
    s8v r;
    r[0] = f2b(a.x); r[1] = f2b(a.y); r[2] = f2b(a.z); r[3] = f2b(a.w);
    r[4] = f2b(b.x); r[5] = f2b(b.y); r[6] = f2b(b.z); r[7] = f2b(b.w);
    return r;
}

// ---------------------------------------------------------------------------
// Kernel 1: up router + up experts + gelu  ->  h (fp32 [N][4096])  [unchanged R3]
// ---------------------------------------------------------------------------
__global__ __launch_bounds__(256, 3) void up_kernel(
    const float* __restrict__ x, const float* __restrict__ Wup,
    const float* __restrict__ Aup, const float* __restrict__ Bup,
    const float* __restrict__ scale_up, const float* __restrict__ bias_up,
    float* __restrict__ h)
{
    __shared__ __align__(16) float xs[TB1 * 1024];
    __shared__ __align__(16) float buf[6912];
    __shared__ __align__(16) float lp[4 * TB1 * 64];
    __shared__ __align__(16) float logits[TB1 * 64];
    __shared__ int   seli[TB1 * 2];
    __shared__ float selp[TB1 * 2];

    const int tid = threadIdx.x;
    const long long blockTok = (long long)blockIdx.x * TB1;

    {
        const float* src = x + blockTok * 1024;
#pragma unroll
        for (int q = 0; q < TB1; ++q) {
            int flat = tid * 4 + q * 1024;
            *(float4*)&xs[flat] = ldg4(src + flat);
        }
    }

    float racc0[TB1] = {0.f, 0.f, 0.f, 0.f};
    float racc1[TB1] = {0.f, 0.f, 0.f, 0.f};
    float* wcs = buf;
    const int e2 = tid & 31, jsl = tid >> 5;
    for (int kc = 0; kc < 1024; kc += 64) {
        __syncthreads();
#pragma unroll
        for (int r = 0; r < 4; ++r) {
            int row = (tid >> 4) + r * 16;
            int col = (tid & 15) * 4;
            *(float4*)&wcs[row * 68 + col] = ldg4(&Wup[row * 1024 + kc + col]);
        }
        __syncthreads();
#pragma unroll
        for (int ks = 0; ks < 2; ++ks) {
            int kk = jsl * 8 + ks * 4;
            float4 w0 = *(float4*)&wcs[e2 * 68 + kk];
            float4 w1 = *(float4*)&wcs[(e2 + 32) * 68 + kk];
#pragma unroll
            for (int t = 0; t < TB1; ++t) {
                float4 xv = *(float4*)&xs[t * 1024 + kc + kk];
                racc0[t] += w0.x * xv.x + w0.y * xv.y + w0.z * xv.z + w0.w * xv.w;
                racc1[t] += w1.x * xv.x + w1.y * xv.y + w1.z * xv.z + w1.w * xv.w;
            }
        }
    }
#pragma unroll
    for (int t = 0; t < TB1; ++t) {
        racc0[t] += __shfl_xor(racc0[t], 32);
        racc1[t] += __shfl_xor(racc1[t], 32);
    }
    {
        const int wv = tid >> 6;
        if ((tid & 32) == 0) {
#pragma unroll
            for (int t = 0; t < TB1; ++t) {
                lp[(wv * TB1 + t) * 64 + e2]      = racc0[t];
                lp[(wv * TB1 + t) * 64 + e2 + 32] = racc1[t];
            }
        }
    }
    __syncthreads();
    logits[tid] = lp[0 * 256 + tid] + lp[1 * 256 + tid] + lp[2 * 256 + tid] + lp[3 * 256 + tid];
    __syncthreads();
    if (tid < TB1) {
        const float* lg = &logits[tid * 64];
        float v0 = -1e30f; int i0 = 0;
        for (int q = 0; q < 64; ++q) { float v = lg[q]; if (v > v0) { v0 = v; i0 = q; } }
        float v1 = -1e30f; int i1 = 0;
        for (int q = 0; q < 64; ++q) { if (q == i0) continue; float v = lg[q]; if (v > v1) { v1 = v; i1 = q; } }
        float r = expf(v1 - v0);
        float inv = 1.f / (1.f + r);
        seli[tid * 2] = i0; seli[tid * 2 + 1] = i1;
        selp[tid * 2] = inv; selp[tid * 2 + 1] = r * inv;
    }
    __syncthreads();

    float* as_ = buf;
    float* bs_ = buf + 2304;
    float* t1_ = buf + 4608;
    const float sc_up = scale_up[0];

    for (int t = 0; t < TB1; ++t) {
        float acc[16];
#pragma unroll
        for (int q = 0; q < 16; ++q) acc[q] = 0.f;

        for (int ke = 0; ke < 2; ++ke) {
            __syncthreads();
            int ex = seli[t * 2 + ke];
            float pw = selp[t * 2 + ke];
            {
                const float* A = Aup + ex * 2048;
                const float* B = Bup + ex * 2048;
#pragma unroll
                for (int q = 0; q < 2; ++q) {
                    int flat = tid * 4 + q * 1024;
                    int r = flat >> 5, c = flat & 31;
                    *(float4*)&as_[r * 36 + c] = ldg4(A + flat);
                    float4 bv = ldg4(B + flat);
                    bv.x *= pw; bv.y *= pw; bv.z *= pw; bv.w *= pw;
                    *(float4*)&bs_[r * 36 + c] = bv;
                }
            }
            __syncthreads();
            {
                int og = tid >> 3, j0 = (tid & 7) * 4;
                float4 s0 = make_float4(0.f, 0.f, 0.f, 0.f);
                float4 s1 = make_float4(0.f, 0.f, 0.f, 0.f);
#pragma unroll 8
                for (int i = 0; i < 32; ++i) {
                    float a0 = as_[og * 36 + i];
                    float a1 = as_[(og + 32) * 36 + i];
                    float4 xv = *(float4*)&xs[t * 1024 + i * 32 + j0];
                    s0.x += a0 * xv.x; s0.y += a0 * xv.y; s0.z += a0 * xv.z; s0.w += a0 * xv.w;
                    s1.x += a1 * xv.x; s1.y += a1 * xv.y; s1.z += a1 * xv.z; s1.w += a1 * xv.w;
                }
                *(float4*)&t1_[og * 36 + j0] = s0;
                *(float4*)&t1_[(og + 32) * 36 + j0] = s1;
            }
            __syncthreads();
            {
                int o0 = tid >> 4, p0 = tid & 15;
#pragma unroll 1
                for (int jq = 0; jq < 8; ++jq) {
                    int j = jq * 4;
                    float4 t0 = *(float4*)&t1_[o0 * 36 + j];
                    float4 t1v = *(float4*)&t1_[(o0 + 16) * 36 + j];
                    float4 t2 = *(float4*)&t1_[(o0 + 32) * 36 + j];
                    float4 t3 = *(float4*)&t1_[(o0 + 48) * 36 + j];
#pragma unroll
                    for (int b = 0; b < 4; ++b) {
                        float4 bv = *(float4*)&bs_[(p0 + 16 * b) * 36 + j];
                        acc[0 * 4 + b] += t0.x * bv.x + t0.y * bv.y + t0.z * bv.z + t0.w * bv.w;
                        acc[1 * 4 + b] += t1v.x * bv.x + t1v.y * bv.y + t1v.z * bv.z + t1v.w * bv.w;
                        acc[2 * 4 + b] += t2.x * bv.x + t2.y * bv.y + t2.z * bv.z + t2.w * bv.w;
                        acc[3 * 4 + b] += t3.x * bv.x + t3.y * bv.y + t3.z * bv.z + t3.w * bv.w;
                    }
                }
            }
        }
        __syncthreads();
        {
            float* yl = buf;
            int o0 = tid >> 4, p0 = tid & 15;
#pragma unroll
            for (int a = 0; a < 4; ++a)
#pragma unroll
                for (int b = 0; b < 4; ++b)
                    yl[(o0 + 16 * a) * 68 + (p0 + 16 * b)] = acc[a * 4 + b] * sc_up;
        }
        __syncthreads();
        {
            long long tok = blockTok + t;
            float* hrow = h + tok * 4096;
            float* yl = buf;
#pragma unroll
            for (int q = 0; q < 4; ++q) {
                int f = q * 1024 + tid * 4;
                int o = f >> 6, p = f & 63;
                float4 v = *(float4*)&yl[o * 68 + p];
                float4 bb = ldg4(&bias_up[f]);
                float4 g;
                float z;
                z = v.x + bb.x; g.x = 0.5f * z * (1.0f + erff(z * 0.70710678118654752f));
                z = v.y + bb.y; g.y = 0.5f * z * (1.0f + erff(z * 0.70710678118654752f));
                z = v.z + bb.z; g.z = 0.5f * z * (1.0f + erff(z * 0.70710678118654752f));
                z = v.w + bb.w; g.w = 0.5f * z * (1.0f + erff(z * 0.70710678118654752f));
                *(float4*)&hrow[f] = g;
            }
        }
    }
}

// ---------------------------------------------------------------------------
// Kernel 2: down router (4 experts/thread) + down experts (bf16 MFMA, per-wave)
// ---------------------------------------------------------------------------
__global__ __launch_bounds__(256, 2) void down_kernel(
    const float* __restrict__ h,        // [N][4096]
    const float* __restrict__ Wdn,      // [64][4096]
    const float* __restrict__ Adn,      // [64][32][64]
    const float* __restrict__ Bdn,      // [64][32][64]
    const float* __restrict__ scale_dn, // [1]
    const float* __restrict__ bias_dn,  // [1024]
    float* __restrict__ out)            // [N][1024]
{
    __shared__ __align__(16) float wcs[64 * 68];    // 17.4 KB
    __shared__ __align__(16) float hcs[16 * 68];    // 4.3 KB
    __shared__ __align__(16) float lp[4 * 16 * 64]; // 16.4 KB
    __shared__ __align__(16) float logits[TB2 * 64];
    __shared__ __align__(16) short wt[4][32 * 72];  // per-wave W^T bf16 [p][i], 4.6 KB each
    __shared__ int   seli[TB2 * 2];
    __shared__ float selp[TB2 * 2];

    const int tid = threadIdx.x;
    const long long tokbase = (long long)blockIdx.x * TB2;

    // ---- down router: 4 experts per thread, k-slice = one float4 ----
    const int e4 = tid & 15, jsl = tid >> 4; // jsl 0..15
    float r0[16], r1[16], r2[16], r3[16];
#pragma unroll
    for (int t = 0; t < 16; ++t) { r0[t] = 0.f; r1[t] = 0.f; r2[t] = 0.f; r3[t] = 0.f; }

    for (int kc = 0; kc < 4096; kc += 64) {
        __syncthreads();
#pragma unroll
        for (int r = 0; r < 4; ++r) {
            int row = (tid >> 4) + r * 16;
            int col = (tid & 15) * 4;
            *(float4*)&wcs[row * 68 + col] = ldg4(&Wdn[row * 4096 + kc + col]);
        }
        {
            int t = tid >> 4, c = (tid & 15) * 4;
            *(float4*)&hcs[t * 68 + c] = ldg4(&h[(tokbase + t) * 4096 + kc + c]);
        }
        __syncthreads();
        const int kk = jsl * 4;
        float4 w0 = *(float4*)&wcs[(e4)      * 68 + kk];
        float4 w1 = *(float4*)&wcs[(e4 + 16) * 68 + kk];
        float4 w2 = *(float4*)&wcs[(e4 + 32) * 68 + kk];
        float4 w3 = *(float4*)&wcs[(e4 + 48) * 68 + kk];
#pragma unroll
        for (int t = 0; t < 16; ++t) {
            float4 hv = *(float4*)&hcs[t * 68 + kk];
            r0[t] += w0.x * hv.x + w0.y * hv.y + w0.z * hv.z + w0.w * hv.w;
            r1[t] += w1.x * hv.x + w1.y * hv.y + w1.z * hv.z + w1.w * hv.w;
            r2[t] += w2.x * hv.x + w2.y * hv.y + w2.z * hv.z + w2.w * hv.w;
            r3[t] += w3.x * hv.x + w3.y * hv.y + w3.z * hv.z + w3.w * hv.w;
        }
    }
    // reduce over the wave's 4 k-slices (lanes xor 16, 32)
#pragma unroll
    for (int t = 0; t < 16; ++t) {
        r0[t] += __shfl_xor(r0[t], 16); r0[t] += __shfl_xor(r0[t], 32);
        r1[t] += __shfl_xor(r1[t], 16); r1[t] += __shfl_xor(r1[t], 32);
        r2[t] += __shfl_xor(r2[t], 16); r2[t] += __shfl_xor(r2[t], 32);
        r3[t] += __shfl_xor(r3[t], 16); r3[t] += __shfl_xor(r3[t], 32);
    }
    {
        const int wv = tid >> 6, g = (tid >> 4) & 3;
        float* dst = &lp[wv * 1024];
        if (g == 0) {
#pragma unroll
            for (int t = 0; t < 16; ++t) dst[t * 64 + e4] = r0[t];
        } else if (g == 1) {
#pragma unroll
            for (int t = 0; t < 16; ++t) dst[t * 64 + 16 + e4] = r1[t];
        } else if (g == 2) {
#pragma unroll
            for (int t = 0; t < 16; ++t) dst[t * 64 + 32 + e4] = r2[t];
        } else {
#pragma unroll
            for (int t = 0; t < 16; ++t) dst[t * 64 + 48 + e4] = r3[t];
        }
    }
    __syncthreads();
#pragma unroll
    for (int q = 0; q < 4; ++q) {
        int pair = tid + q * 256;
        logits[pair] = lp[0 * 1024 + pair] + lp[1 * 1024 + pair] +
                       lp[2 * 1024 + pair] + lp[3 * 1024 + pair];
    }
    __syncthreads();
    if (tid < TB2) {
        const float* lg = &logits[tid * 64];
        float v0 = -1e30f; int i0 = 0;
        for (int q = 0; q < 64; ++q) { float v = lg[q]; if (v > v0) { v0 = v; i0 = q; } }
        float v1 = -1e30f; int i1 = 0;
        for (int q = 0; q < 64; ++q) { if (q == i0) continue; float v = lg[q]; if (v > v1) { v1 = v; i1 = q; } }
        float r = expf(v1 - v0);
        float inv = 1.f / (1.f + r);
        seli[tid * 2] = i0; seli[tid * 2 + 1] = i1;
        selp[tid * 2] = inv; selp[tid * 2 + 1] = r * inv;
    }
    __syncthreads();

    // ---- down experts: per-wave MFMA, no barriers ----
    // W = X · Bdn^T  (stage 1), Y = Adn · W (stage 2), pw folded into W's bf16.
    const float sc_dn = scale_dn[0];
    const int wv = tid >> 6;
    const int lane = tid & 63;
    const int m = lane & 15, quad = lane >> 4;
    short* wtw = &wt[wv][0]; // [32 p][72 i] bf16

    const f4v zf = {0.f, 0.f, 0.f, 0.f};

#pragma unroll 1
    for (int tt = 0; tt < 4; ++tt) {
        const int t = wv * 4 + tt;
        const long long tok = tokbase + t;
        const float* xrow = h + tok * 4096; // X[64 i][64 j], j contiguous

        // X A-operand frags, kept in VGPRs across both experts:
        // xf[mt][ks]: X[m_row = mt*16 + m][k = ks*32 + quad*8 + 0..7]
        s8v xf[8];
#pragma unroll
        for (int mt = 0; mt < 4; ++mt)
#pragma unroll
            for (int ks = 0; ks < 2; ++ks) {
                int base = (mt * 16 + m) * 64 + ks * 32 + quad * 8;
                xf[mt * 2 + ks] = pack8(ldg4(xrow + base), ldg4(xrow + base + 4));
            }

        f4v y00 = zf, y01 = zf, y10 = zf, y11 = zf; // Y tiles (m0,n0)

        for (int ke = 0; ke < 2; ++ke) {
            const int ex = seli[t * 2 + ke];
            const float pw = selp[t * 2 + ke];
            const float* A = Adn + ex * 2048; // [32 o][64 i]
            const float* B = Bdn + ex * 2048; // [32 p][64 j]

            // ---- stage 1: W[i][p] = sum_j X[i][j] * B[p][j] ----
            f4v wd[8]; // tiles (mt: i, pt: p)
#pragma unroll
            for (int ks = 0; ks < 2; ++ks) {
                s8v bf0, bf1;
                {
                    int base = (0 * 16 + m) * 64 + ks * 32 + quad * 8;
                    bf0 = pack8(ldg4(B + base), ldg4(B + base + 4));
                    base = (1 * 16 + m) * 64 + ks * 32 + quad * 8;
                    bf1 = pack8(ldg4(B + base), ldg4(B + base + 4));
                }
#pragma unroll
                for (int mt = 0; mt < 4; ++mt) {
                    wd[mt * 2 + 0] = __builtin_amdgcn_mfma_f32_16x16x32_bf16(
                        xf[mt * 2 + ks], bf0, ks == 0 ? zf : wd[mt * 2 + 0], 0, 0, 0);
                    wd[mt * 2 + 1] = __builtin_amdgcn_mfma_f32_16x16x32_bf16(
                        xf[mt * 2 + ks], bf1, ks == 0 ? zf : wd[mt * 2 + 1], 0, 0, 0);
                }
            }
            // write W^T[p][i] bf16 (pw folded): lane holds W[i=mt*16+quad*4+r][p=pt*16+m]
#pragma unroll
            for (int mt = 0; mt < 4; ++mt)
#pragma unroll
                for (int pt = 0; pt < 2; ++pt) {
                    f4v w = wd[mt * 2 + pt];
                    s4v s;
                    s[0] = f2b(w[0] * pw); s[1] = f2b(w[1] * pw);
                    s[2] = f2b(w[2] * pw); s[3] = f2b(w[3] * pw);
                    *(s4v*)&wtw[(pt * 16 + m) * 72 + mt * 16 + quad * 4] = s;
                }

            // ---- stage 2: Y[o][p] += sum_i A[o][i] * (pw*W)[i][p] ----
#pragma unroll
            for (int ks = 0; ks < 2; ++ks) {
                s8v wb0 = *(s8v*)&wtw[(0 * 16 + m) * 72 + ks * 32 + quad * 8];
                s8v wb1 = *(s8v*)&wtw[(1 * 16 + m) * 72 + ks * 32 + quad * 8];
                s8v af0, af1;
                {
                    int base = (0 * 16 + m) * 64 + ks * 32 + quad * 8;
                    af0 = pack8(ldg4(A + base), ldg4(A + base + 4));
                    base = (1 * 16 + m) * 64 + ks * 32 + quad * 8;
                    af1 = pack8(ldg4(A + base), ldg4(A + base + 4));
                }
                y00 = __builtin_amdgcn_mfma_f32_16x16x32_bf16(af0, wb0, y00, 0, 0, 0);
                y01 = __builtin_amdgcn_mfma_f32_16x16x32_bf16(af0, wb1, y01, 0, 0, 0);
                y10 = __builtin_amdgcn_mfma_f32_16x16x32_bf16(af1, wb0, y10, 0, 0, 0);
                y11 = __builtin_amdgcn_mfma_f32_16x16x32_bf16(af1, wb1, y11, 0, 0, 0);
            }
        }

        // epilogue: Y[o = m0*16 + quad*4 + r][p = n0*16 + m] -> out[tok][o*32+p]
        float* orow = out + tok * 1024;
#pragma unroll
        for (int r = 0; r < 4; ++r) {
            int o0 = quad * 4 + r;
            int f00 = o0 * 32 + m;
            orow[f00]            = y00[r] * sc_dn + bias_dn[f00];
            orow[f00 + 16]       = y01[r] * sc_dn + bias_dn[f00 + 16];
            int f10 = (o0 + 16) * 32 + m;
            orow[f10]            = y10[r] * sc_dn + bias_dn[f10];
            orow[f10 + 16]       = y11[r] * sc_dn + bias_dn[f10 + 16];
        }
    }
}

extern "C" void kernel_launch(void* const* d_in, const int* in_sizes, int n_in,
                              void* d_out, int out_size, void* d_ws, size_t ws_size,
                              hipStream_t stream) {
    const float* x   = (const float*)d_in[0];
    const float* Wup = (const float*)d_in[1];
    const float* Aup = (const float*)d_in[2];
    const float* Bup = (const float*)d_in[3];
    const float* scu = (const float*)d_in[4];
    const float* biu = (const float*)d_in[5];
    const float* Wdn = (const float*)d_in[6];
    const float* Adn = (const float*)d_in[7];
    const float* Bdn = (const float*)d_in[8];
    const float* scd = (const float*)d_in[9];
    const float* bid = (const float*)d_in[10];
    float* out = (float*)d_out;
    float* h   = (float*)d_ws;   // [N][4096] fp32 = 128 MB for N=8192

    const int N = in_sizes[0] / 1024;

    hipLaunchKernelGGL(up_kernel, dim3(N / TB1), dim3(256), 0, stream,
                       x, Wup, Aup, Bup, scu, biu, h);
    hipLaunchKernelGGL(down_kernel, dim3(N / TB2), dim3(256), 0, stream,
                       h, Wdn, Adn, Bdn, scd, bid, out);
}